// Round 2
// baseline (16.962 us; speedup 1.0000x reference)
//
#include <hip/hip_runtime.h>

// Closed-form collapse of the 8-qubit circuit (per 8-wide head group):
//   z0 = cos(x4)*cos(x0+p0)
//   z1 = cos(x1)
//   z2 = cos(x1)*cos(x2)
//   z3 = cos(p1)*cos(x3)
//   z4 = cos(x4)
//   z5 = cos(x5)
//   z6 = cos(x6+p3)
//   z7 = cos(p4)*cos(x7)
// then out[row] = q[row] @ W^T + b   (64x64 GEMV per row)

#define BLOCK 256
#define WAVES 4
#define ROWS_PER_WAVE 2
#define ROWS_PER_BLOCK (WAVES * ROWS_PER_WAVE)   // 8 -> 1024 blocks for 8192 rows

__global__ __launch_bounds__(BLOCK) void qattn_kernel(
    const float* __restrict__ x,      // (rows, 64)
    const float* __restrict__ W,      // (64, 64) row-major: W[j][k]
    const float* __restrict__ bvec,   // (64,)
    const float* __restrict__ qp,     // (6,)
    float* __restrict__ out,          // (rows, 64)
    int nrows)
{
    // one 64-float slot per (wave, row) -> no LDS WAR serialization
    __shared__ float qbuf[WAVES][ROWS_PER_WAVE][64];

    const int lane = threadIdx.x & 63;
    const int wv   = threadIdx.x >> 6;

    // Each lane keeps its output-column's W row in registers (16 float4).
    float4 wreg[16];
    const float4* W4 = reinterpret_cast<const float4*>(W + lane * 64);
    #pragma unroll
    for (int kk = 0; kk < 16; ++kk) wreg[kk] = W4[kk];

    const float bias = bvec[lane];
    const float p0 = qp[0], p1 = qp[1], p3 = qp[3], p4 = qp[4];
    const float cp1 = __cosf(p1);
    const float cp4 = __cosf(p4);

    const int i    = lane & 7;     // wire index within head
    const int base = lane & ~7;    // first lane of this head's 8-angle group
    const float add = (i == 0) ? p0 : (i == 6) ? p3 : 0.0f;

    const int row0 = (blockIdx.x * WAVES + wv) * ROWS_PER_WAVE;

    // ---- phase 1: issue all independent x loads ----
    float xv[ROWS_PER_WAVE];
    #pragma unroll
    for (int r = 0; r < ROWS_PER_WAVE; ++r) {
        const int row = row0 + r;
        xv[r] = (row < nrows) ? x[row * 64 + lane] : 0.0f;
    }

    // ---- phase 2: elementwise quantum expectations ----
    #pragma unroll
    for (int r = 0; r < ROWS_PER_WAVE; ++r) {
        const float xo4 = __shfl(xv[r], base + 4, 64);  // x[h,4] for i==0
        const float xo1 = __shfl(xv[r], base + 1, 64);  // x[h,1] for i==2
        float fac = 1.0f;
        if      (i == 0) fac = __cosf(xo4);
        else if (i == 2) fac = __cosf(xo1);
        else if (i == 3) fac = cp1;
        else if (i == 7) fac = cp4;
        qbuf[wv][r][lane] = fac * __cosf(xv[r] + add);
    }

    // ---- phase 3: interleaved GEMV chains (2 independent accumulators) ----
    float acc[ROWS_PER_WAVE];
    #pragma unroll
    for (int r = 0; r < ROWS_PER_WAVE; ++r) acc[r] = bias;

    #pragma unroll
    for (int kk = 0; kk < 16; ++kk) {
        #pragma unroll
        for (int r = 0; r < ROWS_PER_WAVE; ++r) {
            const float4 qq = reinterpret_cast<const float4*>(qbuf[wv][r])[kk];
            acc[r] = fmaf(qq.x, wreg[kk].x, acc[r]);
            acc[r] = fmaf(qq.y, wreg[kk].y, acc[r]);
            acc[r] = fmaf(qq.z, wreg[kk].z, acc[r]);
            acc[r] = fmaf(qq.w, wreg[kk].w, acc[r]);
        }
    }

    #pragma unroll
    for (int r = 0; r < ROWS_PER_WAVE; ++r) {
        const int row = row0 + r;
        if (row < nrows) out[row * 64 + lane] = acc[r];
    }
}

extern "C" void kernel_launch(void* const* d_in, const int* in_sizes, int n_in,
                              void* d_out, int out_size, void* d_ws, size_t ws_size,
                              hipStream_t stream) {
    const float* x  = (const float*)d_in[0];   // (B,S,E) = (8,1024,64)
    const float* W  = (const float*)d_in[1];   // (64,64)
    const float* b  = (const float*)d_in[2];   // (64,)
    const float* qp = (const float*)d_in[3];   // (6,)
    float* out = (float*)d_out;                // (8,1024,64)

    const int nrows  = in_sizes[0] / 64;       // B*S = 8192
    const int blocks = (nrows + ROWS_PER_BLOCK - 1) / ROWS_PER_BLOCK;  // 1024

    qattn_kernel<<<blocks, BLOCK, 0, stream>>>(x, W, b, qp, out, nrows);
}

// Round 3
// 16.047 us; speedup vs baseline: 1.0570x; 1.0570x over previous
//
#include <hip/hip_runtime.h>

// Closed-form collapse of the 8-qubit circuit (per 8-wide head group):
//   z0 = cos(x4)*cos(x0+p0)
//   z1 = cos(x1)
//   z2 = cos(x1)*cos(x2)
//   z3 = cos(p1)*cos(x3)
//   z4 = cos(x4)
//   z5 = cos(x5)
//   z6 = cos(x6+p3)
//   z7 = cos(p4)*cos(x7)
// then out[row] = q[row] @ W^T + b   (64x64 GEMV per row)
//
// Vectorized layout: one float4 load per lane covers a wave's 4 rows
// (64 lanes x 4 floats = 256 = 4 rows of 64). Even lanes hold wires 0-3
// of one head, odd lanes hold wires 4-7 of the SAME head -> the only
// cross-lane dependency (z0 needs cos(x4)) is one __shfl_xor(.,1).

#define BLOCK 256
#define WAVES 4
#define ROWS_PER_WAVE 4
#define ROWS_PER_BLOCK (WAVES * ROWS_PER_WAVE)   // 16 -> 512 blocks for 8192 rows

__global__ __launch_bounds__(BLOCK) void qattn_kernel(
    const float* __restrict__ x,      // (rows, 64)
    const float* __restrict__ W,      // (64, 64) row-major: W[j][k]
    const float* __restrict__ bvec,   // (64,)
    const float* __restrict__ qp,     // (6,)
    float* __restrict__ out,          // (rows, 64)
    int nrows)
{
    __shared__ float qbuf[WAVES][ROWS_PER_WAVE * 64];

    const int lane = threadIdx.x & 63;
    const int wv   = threadIdx.x >> 6;

    // Each lane keeps its output-column's W row in registers (16 float4).
    float4 wreg[16];
    const float4* W4 = reinterpret_cast<const float4*>(W + lane * 64);
    #pragma unroll
    for (int kk = 0; kk < 16; ++kk) wreg[kk] = W4[kk];

    const float bias = bvec[lane];
    const float p0 = qp[0], p1 = qp[1], p3 = qp[3], p4 = qp[4];
    const float cp1 = __cosf(p1);
    const float cp4 = __cosf(p4);

    const int   parity = lane & 1;               // 0: wires 0-3, 1: wires 4-7
    const float add0 = parity ? 0.0f : p0;       // elem j=0: wire0 gets +p0
    const float add2 = parity ? p3 : 0.0f;       // elem j=2: wire6 gets +p3
    const float wfac = parity ? cp4 : cp1;       // elem j=3: wire7*cp4 / wire3*cp1

    const int row0 = (blockIdx.x * WAVES + wv) * ROWS_PER_WAVE;
    if (row0 >= nrows) return;                   // 8192 % 16 == 0: full groups

    // ---- one vector load covers this wave's 4 rows ----
    const float4 v = reinterpret_cast<const float4*>(x + row0 * 64)[lane];

    const float c0 = __cosf(v.x + add0);
    const float c1 = __cosf(v.y);
    const float c2 = __cosf(v.z + add2);
    const float c3 = __cosf(v.w);
    const float other = __shfl_xor(c0, 1, 64);   // even lane <- cos(x4) of its head

    float4 q;
    q.x = parity ? c0 : other * c0;              // z4 | z0
    q.y = c1;                                    // z5 | z1
    q.z = parity ? c2 : c1 * c2;                 // z6 | z2
    q.w = wfac * c3;                             // z7 | z3

    // wave-private LDS scratch; in-wave ds ordering handled by compiler waitcnts
    reinterpret_cast<float4*>(qbuf[wv])[lane] = q;

    // ---- 4-row GEMV: 4 independent FMA chains, broadcast LDS reads ----
    float acc[ROWS_PER_WAVE] = {bias, bias, bias, bias};
    #pragma unroll
    for (int kk = 0; kk < 16; ++kk) {
        #pragma unroll
        for (int r = 0; r < ROWS_PER_WAVE; ++r) {
            const float4 qq = reinterpret_cast<const float4*>(qbuf[wv] + r * 64)[kk];
            acc[r] = fmaf(qq.x, wreg[kk].x, acc[r]);
            acc[r] = fmaf(qq.y, wreg[kk].y, acc[r]);
            acc[r] = fmaf(qq.z, wreg[kk].z, acc[r]);
            acc[r] = fmaf(qq.w, wreg[kk].w, acc[r]);
        }
    }

    #pragma unroll
    for (int r = 0; r < ROWS_PER_WAVE; ++r)
        out[(row0 + r) * 64 + lane] = acc[r];    // coalesced 256B row stores
}

extern "C" void kernel_launch(void* const* d_in, const int* in_sizes, int n_in,
                              void* d_out, int out_size, void* d_ws, size_t ws_size,
                              hipStream_t stream) {
    const float* x  = (const float*)d_in[0];   // (B,S,E) = (8,1024,64)
    const float* W  = (const float*)d_in[1];   // (64,64)
    const float* b  = (const float*)d_in[2];   // (64,)
    const float* qp = (const float*)d_in[3];   // (6,)
    float* out = (float*)d_out;                // (8,1024,64)

    const int nrows  = in_sizes[0] / 64;       // B*S = 8192
    const int blocks = (nrows + ROWS_PER_BLOCK - 1) / ROWS_PER_BLOCK;  // 512

    qattn_kernel<<<blocks, BLOCK, 0, stream>>>(x, W, b, qp, out, nrows);
}

// Round 4
// 12.650 us; speedup vs baseline: 1.3408x; 1.2685x over previous
//
#include <hip/hip_runtime.h>

// Closed-form collapse of the 8-qubit circuit:
//   z0 = cos(x4)*cos(x0+p0)
//   z1 = cos(x1)
//   z2 = cos(x1)*cos(x2)
//   z3 = cos(p1)*cos(x3)
//   z4 = cos(x4)
//   z5 = cos(x5)
//   z6 = cos(x6+p3)
//   z7 = cos(p4)*cos(x7)
// then out[row] = q[row] @ W^T + b   (64x64 GEMV per row)
//
// NOTE: this is the round-1 kernel re-submitted unchanged as an A/B noise
// control: round-1 measured 12.7us, rounds 2/3 (leaner variants) 16-17us.
// Intrinsic work is ~1us; if this re-measures ~16us the session is at the
// launch-overhead measurement floor.

#define BLOCK 256
#define WAVES 4
#define ROWS_PER_WAVE 4
#define ROWS_PER_BLOCK (WAVES * ROWS_PER_WAVE)   // 16

__global__ __launch_bounds__(BLOCK) void qattn_kernel(
    const float* __restrict__ x,      // (rows, 64)
    const float* __restrict__ W,      // (64, 64) row-major: W[j][k]
    const float* __restrict__ bvec,   // (64,)
    const float* __restrict__ qp,     // (6,)
    float* __restrict__ out,          // (rows, 64)
    int nrows)
{
    __shared__ float qbuf[WAVES][64];

    const int lane = threadIdx.x & 63;
    const int wv   = threadIdx.x >> 6;

    // Each lane keeps its output-column's W row in registers (16 float4).
    float4 wreg[16];
    const float4* W4 = reinterpret_cast<const float4*>(W + lane * 64);
    #pragma unroll
    for (int kk = 0; kk < 16; ++kk) wreg[kk] = W4[kk];

    const float bias = bvec[lane];
    const float p0 = qp[0], p1 = qp[1], p3 = qp[3], p4 = qp[4];
    const float cp1 = __cosf(p1);
    const float cp4 = __cosf(p4);

    const int i    = lane & 7;     // wire index within head
    const int base = lane & ~7;    // first lane of this head's 8-angle group
    const float add = (i == 0) ? p0 : (i == 6) ? p3 : 0.0f;

    const int row0 = (blockIdx.x * WAVES + wv) * ROWS_PER_WAVE;

    #pragma unroll
    for (int r = 0; r < ROWS_PER_WAVE; ++r) {
        const int row = row0 + r;
        if (row >= nrows) break;

        // ---- elementwise quantum expectations (coalesced x load) ----
        const float xv  = x[row * 64 + lane];
        const float xo4 = __shfl(xv, base + 4, 64);  // x[h,4] for i==0
        const float xo1 = __shfl(xv, base + 1, 64);  // x[h,1] for i==2
        float fac = 1.0f;
        if      (i == 0) fac = __cosf(xo4);
        else if (i == 2) fac = __cosf(xo1);
        else if (i == 3) fac = cp1;
        else if (i == 7) fac = cp4;
        const float q = fac * __cosf(xv + add);

        // wave-private LDS scratch (no cross-wave sharing -> no barrier
        // needed; in-wave LDS ops are ordered via compiler waitcnts)
        qbuf[wv][lane] = q;

        // ---- 64-wide dot: out[row][lane] = sum_k q[k] * W[lane][k] + b ----
        float acc = bias;
        const float4* q4 = reinterpret_cast<const float4*>(qbuf[wv]);
        #pragma unroll
        for (int kk = 0; kk < 16; ++kk) {
            const float4 qq = q4[kk];   // uniform-address broadcast read
            acc = fmaf(qq.x, wreg[kk].x, acc);
            acc = fmaf(qq.y, wreg[kk].y, acc);
            acc = fmaf(qq.z, wreg[kk].z, acc);
            acc = fmaf(qq.w, wreg[kk].w, acc);
        }
        out[row * 64 + lane] = acc;     // coalesced store
    }
}

extern "C" void kernel_launch(void* const* d_in, const int* in_sizes, int n_in,
                              void* d_out, int out_size, void* d_ws, size_t ws_size,
                              hipStream_t stream) {
    const float* x  = (const float*)d_in[0];   // (B,S,E) = (8,1024,64)
    const float* W  = (const float*)d_in[1];   // (64,64)
    const float* b  = (const float*)d_in[2];   // (64,)
    const float* qp = (const float*)d_in[3];   // (6,)
    float* out = (float*)d_out;                // (8,1024,64)

    const int nrows  = in_sizes[0] / 64;       // B*S = 8192
    const int blocks = (nrows + ROWS_PER_BLOCK - 1) / ROWS_PER_BLOCK;  // 512

    qattn_kernel<<<blocks, BLOCK, 0, stream>>>(x, W, b, qp, out, nrows);
}